// Round 12
// baseline (1556.020 us; speedup 1.0000x reference)
//
#include <hip/hip_runtime.h>

#define S 1024
#define Bb 4
#define Hh 16
#define DHh 64
#define Dm 1024
#define DIi 4096
#define Vv 16000
#define Lll 4

typedef __attribute__((ext_vector_type(4))) float f32x4;
typedef __attribute__((ext_vector_type(8))) __bf16 bf16x8;
typedef __attribute__((ext_vector_type(8))) unsigned short u16x8;
typedef __attribute__((ext_vector_type(4))) unsigned short u16x4;

__device__ __forceinline__ unsigned short f2bf(float f) {
  unsigned int u = __float_as_uint(f);
  u += 0x7fffu + ((u >> 16) & 1u);
  return (unsigned short)(u >> 16);
}
__device__ __forceinline__ float bf2f(unsigned short u) {
  return __uint_as_float(((unsigned int)u) << 16);
}

__device__ __forceinline__ void gload_lds16(const void* g, void* l) {
  __builtin_amdgcn_global_load_lds((const __attribute__((address_space(1))) unsigned int*)g,
                                   (__attribute__((address_space(3))) unsigned int*)l, 16, 0, 0);
}

__device__ __forceinline__ f32x4 mfma_bf16(bf16x8 a, bf16x8 b, f32x4 c) {
  return __builtin_amdgcn_mfma_f32_16x16x32_bf16(a, b, c, 0, 0, 0);
}

// ---------------- embedding (f32 + bf16 out) ----------------
__global__ __launch_bounds__(256) void embed_k(const int* __restrict__ tokens,
                                               const float* __restrict__ we,
                                               float* __restrict__ h,
                                               unsigned short* __restrict__ hb) {
  int row = blockIdx.x;
  int t = threadIdx.x;
  int tok = tokens[row];
  f32x4 v = *(const f32x4*)&we[(long)tok * Dm + t * 4];
  *(f32x4*)&h[(long)row * Dm + t * 4] = v;
  u16x4 r;
#pragma unroll
  for (int e = 0; e < 4; ++e) r[e] = f2bf(v[e]);
  *(u16x4*)&hb[(long)row * Dm + t * 4] = r;
}

// ---------------- sinusoidal r matrix (bf16) ----------------
__global__ __launch_bounds__(256) void posr_k(unsigned short* __restrict__ r) {
  int idx = blockIdx.x * 256 + threadIdx.x;
  int u = idx >> 10, d = idx & 1023;
  float pos = (float)(S - 1 - u);
  int j = d & 511;
  float invf = powf(10000.0f, -(float)j * (1.0f / 512.0f));
  float a = pos * invf;
  r[idx] = f2bf(d < 512 ? sinf(a) : cosf(a));
}

// ---------------- weight convert+transpose: W[K,N] f32 -> WT[N,K] bf16 ----------------
__global__ __launch_bounds__(256) void wcvt_t(const float* __restrict__ W,
                                              unsigned short* __restrict__ WT,
                                              int Kd, int Nd) {
  __shared__ unsigned short tile[32][40];
  int n0 = blockIdx.x * 32, k0 = blockIdx.y * 32;
  const bool inb = n0 < Nd;
  const float* Wb = W + (long)blockIdx.z * Kd * Nd;
  unsigned short* WTb = WT + (long)blockIdx.z * Kd * Nd;
  int t = threadIdx.x;
  int rr = t >> 3, c4 = (t & 7) * 4;
  f32x4 v = {0.f, 0.f, 0.f, 0.f};
  if (inb) v = *(const f32x4*)&Wb[(long)(k0 + rr) * Nd + n0 + c4];
#pragma unroll
  for (int e = 0; e < 4; ++e) tile[rr][c4 + e] = f2bf(v[e]);
  __syncthreads();
  if (t < 128) {
    int n = t >> 2, k8 = (t & 3) * 8;
    u16x8 pk;
#pragma unroll
    for (int e = 0; e < 8; ++e) pk[e] = tile[k8 + e][n];
    *(u16x8*)&WTb[(long)(n0 + n) * Kd + k0 + k8] = pk;
  }
}

// ---------------- 256x256 depth-3 pipelined GEMM (final vocab GEMM) ----------------
template <int EPI>
__global__ __launch_bounds__(512, 2) void gemm256(const unsigned short* __restrict__ A,
                                                  const unsigned short* __restrict__ BT,
                                                  const float* __restrict__ bias,
                                                  void* __restrict__ Cout,
                                                  int M, int N, int K,
                                                  int ntm, int ntn, int morder) {
  __shared__ unsigned short lds[65536];
  unsigned short* Al = lds;
  unsigned short* Bl = lds + 32768;
  const int tid = threadIdx.x, lane = tid & 63, w = tid >> 6;
  const int la = lane & 15, hi = lane >> 4;
  const int nwg = gridDim.x;
  const int qq = nwg >> 3, rr = nwg & 7;
  const int xcd = blockIdx.x & 7, loc = blockIdx.x >> 3;
  const int wg = (xcd < rr ? xcd * (qq + 1) : rr * (qq + 1) + (xcd - rr) * qq) + loc;
  int bm, bn;
  if (morder) { bm = (wg % ntm) * 256; bn = (wg / ntm) * 256; }
  else        { bn = (wg % ntn) * 256; bm = (wg / ntn) * 256; }
  const int wr = w >> 2, wc = w & 3;
  f32x4 acc[8][4] = {};

  const unsigned short* ag = A + (long)(bm + w * 16 + la) * K + hi * 8;
  const unsigned short* bg = BT + (long)(bn + w * 16 + la) * K + hi * 8;
  unsigned short* Asg = Al + w * 512;
  unsigned short* Bsg = Bl + w * 512;
  const unsigned short* Ard = Al + wr * 4096 + lane * 8;
  const unsigned short* Brd = Bl + wc * 2048 + lane * 8;
  const int NT = K >> 5;

#define STAGE(t) { \
    long ko_ = (long)(t) * 32; int bo_ = ((t) & 3) * 8192; \
    gload_lds16(ag + ko_, Asg + bo_); \
    gload_lds16(ag + ko_ + (long)128 * K, Asg + bo_ + 4096); \
    gload_lds16(bg + ko_, Bsg + bo_); \
    gload_lds16(bg + ko_ + (long)128 * K, Bsg + bo_ + 4096); }

#define COMPUTE(t) { \
    const int bo_ = ((t) & 3) * 8192; \
    bf16x8 af[8], bq[4]; \
    _Pragma("unroll") \
    for (int m = 0; m < 8; ++m) af[m] = *(const bf16x8*)(Ard + bo_ + m * 512); \
    _Pragma("unroll") \
    for (int n = 0; n < 4; ++n) bq[n] = *(const bf16x8*)(Brd + bo_ + n * 512); \
    __builtin_amdgcn_s_setprio(1); \
    _Pragma("unroll") \
    for (int m = 0; m < 8; ++m) \
      _Pragma("unroll") \
      for (int n = 0; n < 4; ++n) acc[m][n] = mfma_bf16(af[m], bq[n], acc[m][n]); \
    __builtin_amdgcn_s_setprio(0); }

  STAGE(0); STAGE(1); STAGE(2);
  int t = 0;
  for (; t < NT - 3; ++t) {
    asm volatile("s_waitcnt vmcnt(8)" ::: "memory");
    __builtin_amdgcn_s_barrier();
    __builtin_amdgcn_sched_barrier(0);
    STAGE(t + 3);
    COMPUTE(t);
  }
  asm volatile("s_waitcnt vmcnt(8)" ::: "memory");
  __builtin_amdgcn_s_barrier();
  __builtin_amdgcn_sched_barrier(0);
  COMPUTE(t); ++t;
  asm volatile("s_waitcnt vmcnt(4)" ::: "memory");
  __builtin_amdgcn_s_barrier();
  __builtin_amdgcn_sched_barrier(0);
  COMPUTE(t); ++t;
  asm volatile("s_waitcnt vmcnt(0)" ::: "memory");
  __builtin_amdgcn_s_barrier();
  __builtin_amdgcn_sched_barrier(0);
  COMPUTE(t);
#undef STAGE
#undef COMPUTE

#pragma unroll
  for (int m = 0; m < 8; ++m) {
#pragma unroll
    for (int n = 0; n < 4; ++n) {
      int col = bn + wc * 64 + n * 16 + la;
      if (col < N) {
        float bv = bias[col];
        int row = bm + wr * 128 + m * 16 + hi * 4;
#pragma unroll
        for (int e = 0; e < 4; ++e) {
          float v = acc[m][n][e] + bv;
          if (EPI == 0) {
            ((float*)Cout)[(long)(row + e) * N + col] = v;
          } else if (EPI == 1) {
            ((unsigned short*)Cout)[(long)(row + e) * N + col] = f2bf(v);
          } else {
            float g = 0.5f * v * (1.0f + erff(v * 0.70710678118f));
            ((unsigned short*)Cout)[(long)(row + e) * N + col] = f2bf(g);
          }
        }
      }
    }
  }
}

// ---------------- 128x128 GEMM + granule-XOR swizzle ----------------
// EPI: 0 f32 out, 1 bf16 out, 2 gelu->bf16, 3 fused qkv epilogue
// (q-third -> qw/qr with rwb/rrb add, k-third -> kb in [B,H,S,64], v-third -> vout [S*B,1024])
template <int EPI>
__global__ __launch_bounds__(256) void gemm_bt(const unsigned short* __restrict__ A,
                                               const unsigned short* __restrict__ BT,
                                               const float* __restrict__ bias,
                                               void* __restrict__ Cout,
                                               int M, int N, int K, int ntn,
                                               const float* __restrict__ rwb,
                                               const float* __restrict__ rrb,
                                               unsigned short* __restrict__ qw,
                                               unsigned short* __restrict__ qr,
                                               unsigned short* __restrict__ kb,
                                               unsigned short* __restrict__ vout) {
  __shared__ unsigned short As[128 * 64];
  __shared__ unsigned short Bs[128 * 64];
  const int tid = threadIdx.x;
  const int lane = tid & 63;
  const int w = tid >> 6;
  const int nwg = gridDim.x;
  const int qq = nwg >> 3, rr = nwg & 7;
  const int xcd = blockIdx.x & 7, loc = blockIdx.x >> 3;
  const int wg = (xcd < rr ? xcd * (qq + 1) : rr * (qq + 1) + (xcd - rr) * qq) + loc;
  const int bn = (wg % ntn) * 128, bm = (wg / ntn) * 128;
  const int wr = (w >> 1) * 64, wc = (w & 1) * 64;
  const int la = lane & 15, hi = lane >> 4;
  f32x4 acc[4][4] = {};

  const int rrow = tid >> 3;
  const int rcol = ((tid & 7) ^ (rrow & 7)) * 8;
  const unsigned short* ag = A + (long)(bm + rrow) * K + rcol;
  const unsigned short* bg = BT + (long)(bn + rrow) * K + rcol;
  const int las = la & 7;
  const int ro0 = (hi ^ las) * 8;
  const int ro1 = ((hi + 4) ^ las) * 8;

  for (int k0 = 0; k0 < K; k0 += 64) {
    __syncthreads();
#pragma unroll
    for (int c = 0; c < 4; ++c) {
      gload_lds16(ag + (long)c * 32 * K + k0, &As[c * 2048 + w * 512]);
      gload_lds16(bg + (long)c * 32 * K + k0, &Bs[c * 2048 + w * 512]);
    }
    __syncthreads();
#pragma unroll
    for (int kk = 0; kk < 2; ++kk) {
      const int ro = kk ? ro1 : ro0;
      bf16x8 af[4], bq[4];
#pragma unroll
      for (int mi = 0; mi < 4; ++mi)
        af[mi] = *(const bf16x8*)&As[(wr + mi * 16 + la) * 64 + ro];
#pragma unroll
      for (int ni = 0; ni < 4; ++ni)
        bq[ni] = *(const bf16x8*)&Bs[(wc + ni * 16 + la) * 64 + ro];
#pragma unroll
      for (int mi = 0; mi < 4; ++mi)
#pragma unroll
        for (int ni = 0; ni < 4; ++ni)
          acc[mi][ni] = mfma_bf16(af[mi], bq[ni], acc[mi][ni]);
    }
  }
  const int cr = hi * 4;
#pragma unroll
  for (int mi = 0; mi < 4; ++mi) {
#pragma unroll
    for (int ni = 0; ni < 4; ++ni) {
      int col = bn + wc + ni * 16 + la;
      float bv = bias[col];
      int row = bm + wr + mi * 16 + cr;
      if (EPI == 3) {
        // fused qkv epilogue: col in [0,3072); third-uniform per fragment
        int t3 = col >> 10;
        int c1 = col & 1023;
        int n = c1 >> 6, d = c1 & 63;
        float rw = (t3 == 0) ? rwb[c1] : 0.f;
        float rrv = (t3 == 0) ? rrb[c1] : 0.f;
#pragma unroll
        for (int e = 0; e < 4; ++e) {
          float v = acc[mi][ni][e] + bv;
          int rowe = row + e;
          int s = rowe >> 2, b = rowe & 3;
          long o = ((long)(b * Hh + n) * S + s) * 64 + d;
          if (t3 == 0) {
            qw[o] = f2bf(v + rw);
            qr[o] = f2bf(v + rrv);
          } else if (t3 == 1) {
            kb[o] = f2bf(v);
          } else {
            vout[(long)rowe * 1024 + c1] = f2bf(v);
          }
        }
      } else {
#pragma unroll
        for (int e = 0; e < 4; ++e) {
          float v = acc[mi][ni][e] + bv;
          if (EPI == 0) {
            ((float*)Cout)[(long)(row + e) * N + col] = v;
          } else if (EPI == 1) {
            ((unsigned short*)Cout)[(long)(row + e) * N + col] = f2bf(v);
          } else {
            float g = 0.5f * v * (1.0f + erff(v * 0.70710678118f));
            ((unsigned short*)Cout)[(long)(row + e) * N + col] = f2bf(g);
          }
        }
      }
    }
  }
}

// ---------------- 64x128 GEMM for N=1024 shapes (2 blocks/CU) ----------------
template <int EPI>
__global__ __launch_bounds__(256) void gemm_bt64(const unsigned short* __restrict__ A,
                                                 const unsigned short* __restrict__ BT,
                                                 const float* __restrict__ bias,
                                                 void* __restrict__ Cout,
                                                 int M, int N, int K, int ntn) {
  __shared__ unsigned short As[64 * 64];
  __shared__ unsigned short Bs[128 * 64];
  const int tid = threadIdx.x;
  const int lane = tid & 63;
  const int w = tid >> 6;
  const int nwg = gridDim.x;
  const int qq = nwg >> 3, rr = nwg & 7;
  const int xcd = blockIdx.x & 7, loc = blockIdx.x >> 3;
  const int wg = (xcd < rr ? xcd * (qq + 1) : rr * (qq + 1) + (xcd - rr) * qq) + loc;
  const int bn = (wg % ntn) * 128, bm = (wg / ntn) * 64;
  const int wr = (w >> 1) * 32, wc = (w & 1) * 64;
  const int la = lane & 15, hi = lane >> 4;
  f32x4 acc[2][4] = {};

  const int rrow = tid >> 3;
  const int rcol = ((tid & 7) ^ (rrow & 7)) * 8;
  const unsigned short* ag = A + (long)(bm + rrow) * K + rcol;
  const unsigned short* bg = BT + (long)(bn + rrow) * K + rcol;
  const int las = la & 7;
  const int ro0 = (hi ^ las) * 8;
  const int ro1 = ((hi + 4) ^ las) * 8;

  for (int k0 = 0; k0 < K; k0 += 64) {
    __syncthreads();
#pragma unroll
    for (int c = 0; c < 2; ++c)
      gload_lds16(ag + (long)c * 32 * K + k0, &As[c * 2048 + w * 512]);
#pragma unroll
    for (int c = 0; c < 4; ++c)
      gload_lds16(bg + (long)c * 32 * K + k0, &Bs[c * 2048 + w * 512]);
    __syncthreads();
#pragma unroll
    for (int kk = 0; kk < 2; ++kk) {
      const int ro = kk ? ro1 : ro0;
      bf16x8 af[2], bq[4];
#pragma unroll
      for (int mi = 0; mi < 2; ++mi)
        af[mi] = *(const bf16x8*)&As[(wr + mi * 16 + la) * 64 + ro];
#pragma unroll
      for (int ni = 0; ni < 4; ++ni)
        bq[ni] = *(const bf16x8*)&Bs[(wc + ni * 16 + la) * 64 + ro];
#pragma unroll
      for (int mi = 0; mi < 2; ++mi)
#pragma unroll
        for (int ni = 0; ni < 4; ++ni)
          acc[mi][ni] = mfma_bf16(af[mi], bq[ni], acc[mi][ni]);
    }
  }
  const int cr = hi * 4;
#pragma unroll
  for (int mi = 0; mi < 2; ++mi) {
#pragma unroll
    for (int ni = 0; ni < 4; ++ni) {
      int col = bn + wc + ni * 16 + la;
      float bv = bias[col];
      int row = bm + wr + mi * 16 + cr;
#pragma unroll
      for (int e = 0; e < 4; ++e) {
        float v = acc[mi][ni][e] + bv;
        if (EPI == 0) {
          ((float*)Cout)[(long)(row + e) * N + col] = v;
        } else if (EPI == 1) {
          ((unsigned short*)Cout)[(long)(row + e) * N + col] = f2bf(v);
        } else {
          float g = 0.5f * v * (1.0f + erff(v * 0.70710678118f));
          ((unsigned short*)Cout)[(long)(row + e) * N + col] = f2bf(g);
        }
      }
    }
  }
}

// ---------------- v transpose: vout bf16 [S*B,1024] -> vT[B*H, DH, S] ----------------
__global__ __launch_bounds__(256) void vt_prep(const unsigned short* __restrict__ vin,
                                               unsigned short* __restrict__ vT) {
  __shared__ unsigned short tile[64][72];
  const int it = blockIdx.x, bn = blockIdx.y;
  const int nh = bn & 15, bbv = bn >> 4;
  const int t = threadIdx.x;
  const int i0 = t >> 3, c8 = (t & 7) * 8;
#pragma unroll
  for (int c = 0; c < 2; ++c) {
    int i = i0 + c * 32;
    u16x8 v = *(const u16x8*)&vin[((long)(it * 64 + i) * Bb + bbv) * 1024 + nh * 64 + c8];
    *(u16x8*)&tile[i][c8] = v;
  }
  __syncthreads();
  for (int cc = t; cc < 512; cc += 256) {
    int d = cc >> 3, i8 = (cc & 7) * 8;
    u16x8 pk;
#pragma unroll
    for (int e = 0; e < 8; ++e) pk[e] = tile[i8 + e][d];
    *(u16x8*)&vT[((long)bn * 64 + d) * S + it * 64 + i8] = pk;
  }
}

// ---------------- rk reorder ----------------
__global__ __launch_bounds__(256) void rkb_prep(const unsigned short* __restrict__ rkall,
                                                unsigned short* __restrict__ rkb) {
  int idx = blockIdx.x * 256 + threadIdx.x;
  int d8 = (idx & 7) * 8;
  int u = (idx >> 3) & 1023;
  int nl = idx >> 13;
  int l = nl >> 4, n = nl & 15;
  u16x8 v = *(const u16x8*)&rkall[(long)u * 4096 + l * 1024 + n * 64 + d8];
  *(u16x8*)&rkb[(long)idx * 8] = v;
}

// ---------------- fused rel-attention (flash), longest-first 1024-grid ----------------
// block = (head bn, q-tile it = 15 - blk/64); heavy tiles dispatch first.
// 41KB LDS -> 3 blocks/CU resident; dynamic refill balances (makespan 34 units/CU).
__global__ __launch_bounds__(256) void attn_k(const unsigned short* __restrict__ qw,
                                              const unsigned short* __restrict__ qr,
                                              const unsigned short* __restrict__ kbuf,
                                              const unsigned short* __restrict__ vT,
                                              const unsigned short* __restrict__ rk,
                                              unsigned short* __restrict__ vec) {
  __shared__ unsigned short Ks[2][64 * 64];
  __shared__ unsigned short Vs[2][64 * 64];
  __shared__ unsigned short plds[4][16][72];
  const int tid = threadIdx.x, lane = tid & 63, w = tid >> 6;
  const int bn = blockIdx.x & 63;
  const int it = 15 - (blockIdx.x >> 6);
  const int nh = bn & 15, bbv = bn >> 4;
  const int la = lane & 15, hi = lane >> 4, lk = hi * 8;
  const int hi4 = hi * 4;
  const unsigned short* kbase = kbuf + (long)bn * S * 64;
  const unsigned short* vbase = vT + (long)bn * 64 * S;
  const unsigned short* rbase = rk + (long)nh * S * 64;

  const int q0 = w * 128 + lane;
  const int r0 = q0 >> 3, c0s = (q0 & 7) ^ (r0 & 7);
  const int q1 = q0 + 64;
  const int r1 = q1 >> 3, c1s = (q1 & 7) ^ (r1 & 7);

  const int iw = it * 64 + w * 16;
  bf16x8 qwf[2], qrf[2];
  {
    const unsigned short* qp = qw + ((long)bn * S + iw + la) * 64 + lk;
    qwf[0] = *(const bf16x8*)qp;
    qwf[1] = *(const bf16x8*)(qp + 32);
    const unsigned short* qp2 = qr + ((long)bn * S + iw + la) * 64 + lk;
    qrf[0] = *(const bf16x8*)qp2;
    qrf[1] = *(const bf16x8*)(qp2 + 32);
  }
  f32x4 opv[4] = {};
  float m_ = -3e38f;
  float l_[4] = {0.f, 0.f, 0.f, 0.f};
  int cur = 0;

  gload_lds16(kbase + (long)r0 * 64 + c0s * 8, &Ks[cur][w * 1024]);
  gload_lds16(kbase + (long)r1 * 64 + c1s * 8, &Ks[cur][w * 1024 + 512]);
  gload_lds16(vbase + (long)r0 * S + c0s * 8, &Vs[cur][w * 1024]);
  gload_lds16(vbase + (long)r1 * S + c1s * 8, &Vs[cur][w * 1024 + 512]);
  __syncthreads();

  for (int jt = 0; jt <= it; ++jt) {
    const int j0 = jt * 64;
    const bool edge = (jt == it);
    if (jt < it) {
      const int jn = j0 + 64;
      gload_lds16(kbase + (long)(jn + r0) * 64 + c0s * 8, &Ks[cur ^ 1][w * 1024]);
      gload_lds16(kbase + (long)(jn + r1) * 64 + c1s * 8, &Ks[cur ^ 1][w * 1024 + 512]);
      gload_lds16(vbase + (long)r0 * S + jn + c0s * 8, &Vs[cur ^ 1][w * 1024]);
      gload_lds16(vbase + (long)r1 * S + jn + c1s * 8, &Vs[cur ^ 1][w * 1024 + 512]);
    }
    const int u0 = S - 16 - iw + j0;
    bf16x8 rf[10];
#pragma unroll
    for (int g = 0; g < 5; ++g) {
      int u = u0 + g * 16 + la;
      if (edge) u = (u > S - 1) ? (S - 1) : u;
      const unsigned short* rp = rbase + (long)u * 64 + lk;
      rf[2 * g] = *(const bf16x8*)rp;
      rf[2 * g + 1] = *(const bf16x8*)(rp + 32);
    }
    f32x4 ac[4] = {};
#pragma unroll
    for (int f = 0; f < 4; ++f) {
      int row = f * 16 + la;
      const unsigned short* kl = &Ks[cur][row * 64];
      bf16x8 k0 = *(const bf16x8*)(kl + (((hi) ^ (row & 7)) << 3));
      bf16x8 k1 = *(const bf16x8*)(kl + (((hi + 4) ^ (row & 7)) << 3));
      ac[f] = mfma_bf16(qwf[0], k0, ac[f]);
      ac[f] = mfma_bf16(qwf[1], k1, ac[f]);
    }
    f32x4 gg[5] = {};
#pragma unroll
    for (int g = 0; g < 5; ++g) {
      gg[g] = mfma_bf16(qrf[0], rf[2 * g], gg[g]);
      gg[g] = mfma_bf16(qrf[1], rf[2 * g + 1], gg[g]);
    }
    float p[4][4];
#pragma unroll
    for (int f = 0; f < 4; ++f) {
#pragma unroll
      for (int e = 0; e < 4; ++e) {
        int r = hi4 + e;
        float x = (la >= 15 - r) ? gg[f][e] : gg[f + 1][e];
        int src = (lane & 48) | ((la + 15 - r) & 15);
        float bd = __shfl(x, src, 64);
        float sc = (ac[f][e] + bd) * 0.125f;
        if (edge) {
          int i_ = iw + r, j_ = j0 + f * 16 + la;
          sc = (j_ > i_) ? -1e30f : sc;
        }
        p[f][e] = sc;
      }
    }
    float mx = p[0][0];
#pragma unroll
    for (int f = 0; f < 4; ++f)
#pragma unroll
      for (int e = 0; e < 4; ++e) mx = fmaxf(mx, p[f][e]);
#pragma unroll
    for (int o = 1; o < 16; o <<= 1) mx = fmaxf(mx, __shfl_xor(mx, o, 64));
    if (!__all(mx <= m_ + 8.0f)) {
      float mnew = fmaxf(m_, mx);
      float alpha = __expf(m_ - mnew);
      m_ = mnew;
#pragma unroll
      for (int e = 0; e < 4; ++e) l_[e] *= alpha;
#pragma unroll
      for (int d = 0; d < 4; ++d)
#pragma unroll
        for (int e = 0; e < 4; ++e) opv[d][e] *= alpha;
    }
#pragma unroll
    for (int e = 0; e < 4; ++e) {
      float rs = 0.f;
#pragma unroll
      for (int f = 0; f < 4; ++f) {
        p[f][e] = __expf(p[f][e] - m_);
        rs += p[f][e];
      }
      l_[e] += rs;
    }
#pragma unroll
    for (int f = 0; f < 4; ++f)
#pragma unroll
      for (int e = 0; e < 4; ++e)
        plds[w][hi4 + e][f * 16 + la] = f2bf(p[f][e]);
    bf16x8 pa0 = *(const bf16x8*)&plds[w][la][lk];
    bf16x8 pa1 = *(const bf16x8*)&plds[w][la][32 + lk];
#pragma unroll
    for (int d = 0; d < 4; ++d) {
      int dd = d * 16 + la;
      const unsigned short* vl = &Vs[cur][dd * 64];
      bf16x8 v0 = *(const bf16x8*)(vl + (((hi) ^ (dd & 7)) << 3));
      bf16x8 v1 = *(const bf16x8*)(vl + (((hi + 4) ^ (dd & 7)) << 3));
      opv[d] = mfma_bf16(pa0, v0, opv[d]);
      opv[d] = mfma_bf16(pa1, v1, opv[d]);
    }
    __syncthreads();
    if (jt < it) cur ^= 1;
  }
#pragma unroll
  for (int e = 0; e < 4; ++e) {
#pragma unroll
    for (int o = 1; o < 16; o <<= 1) l_[e] += __shfl_xor(l_[e], o, 64);
  }
#pragma unroll
  for (int d = 0; d < 4; ++d) {
#pragma unroll
    for (int e = 0; e < 4; ++e) {
      int i_ = iw + hi4 + e;
      int col = nh * 64 + d * 16 + la;
      vec[((long)i_ * Bb + bbv) * 1024 + col] = f2bf(opv[d][e] / l_[e]);
    }
  }
}

// ---------------- residual add + layernorm ----------------
__global__ __launch_bounds__(256) void add_ln(float* __restrict__ h, const float* __restrict__ x,
                                              const float* __restrict__ g, const float* __restrict__ b,
                                              unsigned short* __restrict__ hb) {
  __shared__ float red[8];
  int row = blockIdx.x, t = threadIdx.x;
  long base = (long)row * 1024 + t * 4;
  f32x4 hv = *(const f32x4*)&h[base];
  f32x4 xv = *(const f32x4*)&x[base];
  f32x4 y = hv + xv;
  float s = y[0] + y[1] + y[2] + y[3];
  float q = y[0] * y[0] + y[1] * y[1] + y[2] * y[2] + y[3] * y[3];
#pragma unroll
  for (int o = 1; o < 64; o <<= 1) {
    s += __shfl_xor(s, o, 64);
    q += __shfl_xor(q, o, 64);
  }
  int w = t >> 6, lane = t & 63;
  if (lane == 0) { red[w] = s; red[4 + w] = q; }
  __syncthreads();
  s = red[0] + red[1] + red[2] + red[3];
  q = red[4] + red[5] + red[6] + red[7];
  float mu = s * (1.0f / 1024.0f);
  float var = q * (1.0f / 1024.0f) - mu * mu;
  float rstd = rsqrtf(var + 1e-5f);
  f32x4 gv = *(const f32x4*)&g[t * 4];
  f32x4 bv = *(const f32x4*)&b[t * 4];
  f32x4 o;
  u16x4 ob;
#pragma unroll
  for (int e = 0; e < 4; ++e) {
    o[e] = (y[e] - mu) * rstd * gv[e] + bv[e];
    ob[e] = f2bf(o[e]);
  }
  *(f32x4*)&h[base] = o;
  *(u16x4*)&hb[base] = ob;
}

extern "C" void kernel_launch(void* const* d_in, const int* in_sizes, int n_in,
                              void* d_out, int out_size, void* d_ws, size_t ws_size,
                              hipStream_t stream) {
  const int* tokens = (const int*)d_in[0];
  const float* word_emb = (const float*)d_in[1];
  const float* rwb = (const float*)d_in[2];
  const float* rrb = (const float*)d_in[3];
  const float* qkv_w = (const float*)d_in[4];
  const float* qkv_b = (const float*)d_in[5];
  const float* r_kw = (const float*)d_in[6];
  const float* r_kb = (const float*)d_in[7];
  const float* o_w = (const float*)d_in[8];
  const float* o_b = (const float*)d_in[9];
  const float* ln1g = (const float*)d_in[10];
  const float* ln1b = (const float*)d_in[11];
  const float* ff1w = (const float*)d_in[12];
  const float* ff1b = (const float*)d_in[13];
  const float* ff2w = (const float*)d_in[14];
  const float* ff2b = (const float*)d_in[15];
  const float* ln2g = (const float*)d_in[16];
  const float* ln2b = (const float*)d_in[17];
  const float* fw = (const float*)d_in[18];
  const float* fb = (const float*)d_in[19];

  char* ws = (char*)d_ws;
  unsigned short* WBF = (unsigned short*)(ws);               // converted weights [Npad,K]
  float* H = (float*)(ws + 33554432);                        // residual f32
  unsigned short* HB = (unsigned short*)(ws + 50331648);     // activations bf16
  unsigned short* GB = (unsigned short*)(ws + 58720256);     // gelu out bf16
  unsigned short* RBF = (unsigned short*)(ws + 92274688);    // pos-emb bf16

  char* ob = (char*)d_out;
  float* OUTF = (float*)ob;
  unsigned short* OUTH = (unsigned short*)ob;                // also vout (compact v third)
  unsigned short* QW = (unsigned short*)(ob + 67108864);
  unsigned short* QR = (unsigned short*)(ob + 75497472);
  unsigned short* KB = (unsigned short*)(ob + 83886080);
  unsigned short* VT = (unsigned short*)(ob + 92274688);
  unsigned short* RKB = (unsigned short*)(ob + 100663296);
  float* OUT = (float*)d_out;

  embed_k<<<4096, 256, 0, stream>>>(tokens, word_emb, H, HB);
  posr_k<<<4096, 256, 0, stream>>>(RBF);
  wcvt_t<<<dim3(32, 32, 4), 256, 0, stream>>>(r_kw, WBF, 1024, 1024);
  gemm_bt<1><<<256, 256, 0, stream>>>(RBF, WBF, r_kb, OUTH, 1024, 4096, 1024, 32,
                                      nullptr, nullptr, nullptr, nullptr, nullptr, nullptr);
  rkb_prep<<<2048, 256, 0, stream>>>(OUTH, RKB);

  for (int l = 0; l < Lll; ++l) {
    wcvt_t<<<dim3(96, 32, 1), 256, 0, stream>>>(qkv_w + (long)l * 1024 * 3072, WBF, 1024, 3072);
    // fused epilogue: writes QW/QR/KB directly + compact v third into OUTH
    gemm_bt<3><<<768, 256, 0, stream>>>(HB, WBF, qkv_b + l * 3072, nullptr, 4096, 3072, 1024, 24,
                                        rwb, rrb, QW, QR, KB, OUTH);
    vt_prep<<<dim3(16, 64), 256, 0, stream>>>(OUTH, VT);
    attn_k<<<1024, 256, 0, stream>>>(QW, QR, KB, VT, RKB + (long)l * Hh * S * 64, HB);
    wcvt_t<<<dim3(32, 32, 1), 256, 0, stream>>>(o_w + (long)l * 1024 * 1024, WBF, 1024, 1024);
    gemm_bt64<0><<<512, 256, 0, stream>>>(HB, WBF, o_b + l * 1024, OUTF, 4096, 1024, 1024, 8);
    add_ln<<<4096, 256, 0, stream>>>(H, OUTF, ln1g + l * 1024, ln1b + l * 1024, HB);

    wcvt_t<<<dim3(128, 32, 1), 256, 0, stream>>>(ff1w + (long)l * 1024 * 4096, WBF, 1024, 4096);
    gemm_bt<2><<<1024, 256, 0, stream>>>(HB, WBF, ff1b + l * 4096, GB, 4096, 4096, 1024, 32,
                                         nullptr, nullptr, nullptr, nullptr, nullptr, nullptr);
    wcvt_t<<<dim3(32, 128, 1), 256, 0, stream>>>(ff2w + (long)l * 4096 * 1024, WBF, 4096, 1024);
    gemm_bt64<0><<<512, 256, 0, stream>>>(GB, WBF, ff2b + l * 1024, OUTF, 4096, 1024, 4096, 8);
    add_ln<<<4096, 256, 0, stream>>>(H, OUTF, ln2g + l * 1024, ln2b + l * 1024, HB);
  }

  // final: pad N to 16128 (63*256); bm-major for B-panel L2 reuse
  wcvt_t<<<dim3(504, 32, 1), 256, 0, stream>>>(fw, WBF, 1024, 16000);
  gemm256<0><<<1008, 512, 0, stream>>>(HB, WBF, fb, OUT, 4096, 16000, 1024, 16, 63, 1);
}

// Round 13
// 1399.301 us; speedup vs baseline: 1.1120x; 1.1120x over previous
//
#include <hip/hip_runtime.h>

#define S 1024
#define Bb 4
#define Hh 16
#define DHh 64
#define Dm 1024
#define DIi 4096
#define Vv 16000
#define Lll 4

typedef __attribute__((ext_vector_type(4))) float f32x4;
typedef __attribute__((ext_vector_type(8))) __bf16 bf16x8;
typedef __attribute__((ext_vector_type(8))) unsigned short u16x8;
typedef __attribute__((ext_vector_type(4))) unsigned short u16x4;

__device__ __forceinline__ unsigned short f2bf(float f) {
  unsigned int u = __float_as_uint(f);
  u += 0x7fffu + ((u >> 16) & 1u);
  return (unsigned short)(u >> 16);
}
__device__ __forceinline__ float bf2f(unsigned short u) {
  return __uint_as_float(((unsigned int)u) << 16);
}

__device__ __forceinline__ void gload_lds16(const void* g, void* l) {
  __builtin_amdgcn_global_load_lds((const __attribute__((address_space(1))) unsigned int*)g,
                                   (__attribute__((address_space(3))) unsigned int*)l, 16, 0, 0);
}

__device__ __forceinline__ f32x4 mfma_bf16(bf16x8 a, bf16x8 b, f32x4 c) {
  return __builtin_amdgcn_mfma_f32_16x16x32_bf16(a, b, c, 0, 0, 0);
}

// ---------------- embedding (f32 + bf16 out) ----------------
__global__ __launch_bounds__(256) void embed_k(const int* __restrict__ tokens,
                                               const float* __restrict__ we,
                                               float* __restrict__ h,
                                               unsigned short* __restrict__ hb) {
  int row = blockIdx.x;
  int t = threadIdx.x;
  int tok = tokens[row];
  f32x4 v = *(const f32x4*)&we[(long)tok * Dm + t * 4];
  *(f32x4*)&h[(long)row * Dm + t * 4] = v;
  u16x4 r;
#pragma unroll
  for (int e = 0; e < 4; ++e) r[e] = f2bf(v[e]);
  *(u16x4*)&hb[(long)row * Dm + t * 4] = r;
}

// ---------------- sinusoidal r matrix (bf16) ----------------
__global__ __launch_bounds__(256) void posr_k(unsigned short* __restrict__ r) {
  int idx = blockIdx.x * 256 + threadIdx.x;
  int u = idx >> 10, d = idx & 1023;
  float pos = (float)(S - 1 - u);
  int j = d & 511;
  float invf = powf(10000.0f, -(float)j * (1.0f / 512.0f));
  float a = pos * invf;
  r[idx] = f2bf(d < 512 ? sinf(a) : cosf(a));
}

// ---------------- weight convert+transpose: W[K,N] f32 -> WT[N,K] bf16 ----------------
__global__ __launch_bounds__(256) void wcvt_t(const float* __restrict__ W,
                                              unsigned short* __restrict__ WT,
                                              int Kd, int Nd) {
  __shared__ unsigned short tile[32][40];
  int n0 = blockIdx.x * 32, k0 = blockIdx.y * 32;
  const bool inb = n0 < Nd;
  const float* Wb = W + (long)blockIdx.z * Kd * Nd;
  unsigned short* WTb = WT + (long)blockIdx.z * Kd * Nd;
  int t = threadIdx.x;
  int rr = t >> 3, c4 = (t & 7) * 4;
  f32x4 v = {0.f, 0.f, 0.f, 0.f};
  if (inb) v = *(const f32x4*)&Wb[(long)(k0 + rr) * Nd + n0 + c4];
#pragma unroll
  for (int e = 0; e < 4; ++e) tile[rr][c4 + e] = f2bf(v[e]);
  __syncthreads();
  if (t < 128) {
    int n = t >> 2, k8 = (t & 3) * 8;
    u16x8 pk;
#pragma unroll
    for (int e = 0; e < 8; ++e) pk[e] = tile[k8 + e][n];
    *(u16x8*)&WTb[(long)(n0 + n) * Kd + k0 + k8] = pk;
  }
}

// ---------------- 256x256 depth-3 pipelined GEMM (final vocab GEMM) ----------------
template <int EPI>
__global__ __launch_bounds__(512, 2) void gemm256(const unsigned short* __restrict__ A,
                                                  const unsigned short* __restrict__ BT,
                                                  const float* __restrict__ bias,
                                                  void* __restrict__ Cout,
                                                  int M, int N, int K,
                                                  int ntm, int ntn, int morder) {
  __shared__ unsigned short lds[65536];
  unsigned short* Al = lds;
  unsigned short* Bl = lds + 32768;
  const int tid = threadIdx.x, lane = tid & 63, w = tid >> 6;
  const int la = lane & 15, hi = lane >> 4;
  const int nwg = gridDim.x;
  const int qq = nwg >> 3, rr = nwg & 7;
  const int xcd = blockIdx.x & 7, loc = blockIdx.x >> 3;
  const int wg = (xcd < rr ? xcd * (qq + 1) : rr * (qq + 1) + (xcd - rr) * qq) + loc;
  int bm, bn;
  if (morder) { bm = (wg % ntm) * 256; bn = (wg / ntm) * 256; }
  else        { bn = (wg % ntn) * 256; bm = (wg / ntn) * 256; }
  const int wr = w >> 2, wc = w & 3;
  f32x4 acc[8][4] = {};

  const unsigned short* ag = A + (long)(bm + w * 16 + la) * K + hi * 8;
  const unsigned short* bg = BT + (long)(bn + w * 16 + la) * K + hi * 8;
  unsigned short* Asg = Al + w * 512;
  unsigned short* Bsg = Bl + w * 512;
  const unsigned short* Ard = Al + wr * 4096 + lane * 8;
  const unsigned short* Brd = Bl + wc * 2048 + lane * 8;
  const int NT = K >> 5;

#define STAGE(t) { \
    long ko_ = (long)(t) * 32; int bo_ = ((t) & 3) * 8192; \
    gload_lds16(ag + ko_, Asg + bo_); \
    gload_lds16(ag + ko_ + (long)128 * K, Asg + bo_ + 4096); \
    gload_lds16(bg + ko_, Bsg + bo_); \
    gload_lds16(bg + ko_ + (long)128 * K, Bsg + bo_ + 4096); }

#define COMPUTE(t) { \
    const int bo_ = ((t) & 3) * 8192; \
    bf16x8 af[8], bq[4]; \
    _Pragma("unroll") \
    for (int m = 0; m < 8; ++m) af[m] = *(const bf16x8*)(Ard + bo_ + m * 512); \
    _Pragma("unroll") \
    for (int n = 0; n < 4; ++n) bq[n] = *(const bf16x8*)(Brd + bo_ + n * 512); \
    __builtin_amdgcn_s_setprio(1); \
    _Pragma("unroll") \
    for (int m = 0; m < 8; ++m) \
      _Pragma("unroll") \
      for (int n = 0; n < 4; ++n) acc[m][n] = mfma_bf16(af[m], bq[n], acc[m][n]); \
    __builtin_amdgcn_s_setprio(0); }

  STAGE(0); STAGE(1); STAGE(2);
  int t = 0;
  for (; t < NT - 3; ++t) {
    asm volatile("s_waitcnt vmcnt(8)" ::: "memory");
    __builtin_amdgcn_s_barrier();
    __builtin_amdgcn_sched_barrier(0);
    STAGE(t + 3);
    COMPUTE(t);
  }
  asm volatile("s_waitcnt vmcnt(8)" ::: "memory");
  __builtin_amdgcn_s_barrier();
  __builtin_amdgcn_sched_barrier(0);
  COMPUTE(t); ++t;
  asm volatile("s_waitcnt vmcnt(4)" ::: "memory");
  __builtin_amdgcn_s_barrier();
  __builtin_amdgcn_sched_barrier(0);
  COMPUTE(t); ++t;
  asm volatile("s_waitcnt vmcnt(0)" ::: "memory");
  __builtin_amdgcn_s_barrier();
  __builtin_amdgcn_sched_barrier(0);
  COMPUTE(t);
#undef STAGE
#undef COMPUTE

#pragma unroll
  for (int m = 0; m < 8; ++m) {
#pragma unroll
    for (int n = 0; n < 4; ++n) {
      int col = bn + wc * 64 + n * 16 + la;
      if (col < N) {
        float bv = bias[col];
        int row = bm + wr * 128 + m * 16 + hi * 4;
#pragma unroll
        for (int e = 0; e < 4; ++e) {
          float v = acc[m][n][e] + bv;
          if (EPI == 0) {
            ((float*)Cout)[(long)(row + e) * N + col] = v;
          } else if (EPI == 1) {
            ((unsigned short*)Cout)[(long)(row + e) * N + col] = f2bf(v);
          } else {
            float g = 0.5f * v * (1.0f + erff(v * 0.70710678118f));
            ((unsigned short*)Cout)[(long)(row + e) * N + col] = f2bf(g);
          }
        }
      }
    }
  }
}

// ---------------- 128x128 GEMM (r3 pedigree) + granule-XOR swizzle ----------------
template <int EPI>
__global__ __launch_bounds__(256) void gemm_bt(const unsigned short* __restrict__ A,
                                               const unsigned short* __restrict__ BT,
                                               const float* __restrict__ bias,
                                               void* __restrict__ Cout,
                                               int M, int N, int K, int ntn) {
  __shared__ unsigned short As[128 * 64];
  __shared__ unsigned short Bs[128 * 64];
  const int tid = threadIdx.x;
  const int lane = tid & 63;
  const int w = tid >> 6;
  const int nwg = gridDim.x;
  const int qq = nwg >> 3, rr = nwg & 7;
  const int xcd = blockIdx.x & 7, loc = blockIdx.x >> 3;
  const int wg = (xcd < rr ? xcd * (qq + 1) : rr * (qq + 1) + (xcd - rr) * qq) + loc;
  const int bn = (wg % ntn) * 128, bm = (wg / ntn) * 128;
  const int wr = (w >> 1) * 64, wc = (w & 1) * 64;
  const int la = lane & 15, hi = lane >> 4;
  f32x4 acc[4][4] = {};

  const int rrow = tid >> 3;
  const int rcol = ((tid & 7) ^ (rrow & 7)) * 8;
  const unsigned short* ag = A + (long)(bm + rrow) * K + rcol;
  const unsigned short* bg = BT + (long)(bn + rrow) * K + rcol;
  const int las = la & 7;
  const int ro0 = (hi ^ las) * 8;
  const int ro1 = ((hi + 4) ^ las) * 8;

  for (int k0 = 0; k0 < K; k0 += 64) {
    __syncthreads();
#pragma unroll
    for (int c = 0; c < 4; ++c) {
      gload_lds16(ag + (long)c * 32 * K + k0, &As[c * 2048 + w * 512]);
      gload_lds16(bg + (long)c * 32 * K + k0, &Bs[c * 2048 + w * 512]);
    }
    __syncthreads();
#pragma unroll
    for (int kk = 0; kk < 2; ++kk) {
      const int ro = kk ? ro1 : ro0;
      bf16x8 af[4], bq[4];
#pragma unroll
      for (int mi = 0; mi < 4; ++mi)
        af[mi] = *(const bf16x8*)&As[(wr + mi * 16 + la) * 64 + ro];
#pragma unroll
      for (int ni = 0; ni < 4; ++ni)
        bq[ni] = *(const bf16x8*)&Bs[(wc + ni * 16 + la) * 64 + ro];
#pragma unroll
      for (int mi = 0; mi < 4; ++mi)
#pragma unroll
        for (int ni = 0; ni < 4; ++ni)
          acc[mi][ni] = mfma_bf16(af[mi], bq[ni], acc[mi][ni]);
    }
  }
  const int cr = hi * 4;
#pragma unroll
  for (int mi = 0; mi < 4; ++mi) {
#pragma unroll
    for (int ni = 0; ni < 4; ++ni) {
      int col = bn + wc + ni * 16 + la;
      float bv = bias[col];
      int row = bm + wr + mi * 16 + cr;
#pragma unroll
      for (int e = 0; e < 4; ++e) {
        float v = acc[mi][ni][e] + bv;
        if (EPI == 0) {
          ((float*)Cout)[(long)(row + e) * N + col] = v;
        } else if (EPI == 1) {
          ((unsigned short*)Cout)[(long)(row + e) * N + col] = f2bf(v);
        } else {
          float g = 0.5f * v * (1.0f + erff(v * 0.70710678118f));
          ((unsigned short*)Cout)[(long)(row + e) * N + col] = f2bf(g);
        }
      }
    }
  }
}

// ---------------- 64x128 GEMM for N=1024 shapes (2 blocks/CU) ----------------
template <int EPI>
__global__ __launch_bounds__(256) void gemm_bt64(const unsigned short* __restrict__ A,
                                                 const unsigned short* __restrict__ BT,
                                                 const float* __restrict__ bias,
                                                 void* __restrict__ Cout,
                                                 int M, int N, int K, int ntn) {
  __shared__ unsigned short As[64 * 64];
  __shared__ unsigned short Bs[128 * 64];
  const int tid = threadIdx.x;
  const int lane = tid & 63;
  const int w = tid >> 6;
  const int nwg = gridDim.x;
  const int qq = nwg >> 3, rr = nwg & 7;
  const int xcd = blockIdx.x & 7, loc = blockIdx.x >> 3;
  const int wg = (xcd < rr ? xcd * (qq + 1) : rr * (qq + 1) + (xcd - rr) * qq) + loc;
  const int bn = (wg % ntn) * 128, bm = (wg / ntn) * 64;
  const int wr = (w >> 1) * 32, wc = (w & 1) * 64;
  const int la = lane & 15, hi = lane >> 4;
  f32x4 acc[2][4] = {};

  const int rrow = tid >> 3;
  const int rcol = ((tid & 7) ^ (rrow & 7)) * 8;
  const unsigned short* ag = A + (long)(bm + rrow) * K + rcol;
  const unsigned short* bg = BT + (long)(bn + rrow) * K + rcol;
  const int las = la & 7;
  const int ro0 = (hi ^ las) * 8;
  const int ro1 = ((hi + 4) ^ las) * 8;

  for (int k0 = 0; k0 < K; k0 += 64) {
    __syncthreads();
#pragma unroll
    for (int c = 0; c < 2; ++c)
      gload_lds16(ag + (long)c * 32 * K + k0, &As[c * 2048 + w * 512]);
#pragma unroll
    for (int c = 0; c < 4; ++c)
      gload_lds16(bg + (long)c * 32 * K + k0, &Bs[c * 2048 + w * 512]);
    __syncthreads();
#pragma unroll
    for (int kk = 0; kk < 2; ++kk) {
      const int ro = kk ? ro1 : ro0;
      bf16x8 af[2], bq[4];
#pragma unroll
      for (int mi = 0; mi < 2; ++mi)
        af[mi] = *(const bf16x8*)&As[(wr + mi * 16 + la) * 64 + ro];
#pragma unroll
      for (int ni = 0; ni < 4; ++ni)
        bq[ni] = *(const bf16x8*)&Bs[(wc + ni * 16 + la) * 64 + ro];
#pragma unroll
      for (int mi = 0; mi < 2; ++mi)
#pragma unroll
        for (int ni = 0; ni < 4; ++ni)
          acc[mi][ni] = mfma_bf16(af[mi], bq[ni], acc[mi][ni]);
    }
  }
  const int cr = hi * 4;
#pragma unroll
  for (int mi = 0; mi < 2; ++mi) {
#pragma unroll
    for (int ni = 0; ni < 4; ++ni) {
      int col = bn + wc + ni * 16 + la;
      float bv = bias[col];
      int row = bm + wr + mi * 16 + cr;
#pragma unroll
      for (int e = 0; e < 4; ++e) {
        float v = acc[mi][ni][e] + bv;
        if (EPI == 0) {
          ((float*)Cout)[(long)(row + e) * N + col] = v;
        } else if (EPI == 1) {
          ((unsigned short*)Cout)[(long)(row + e) * N + col] = f2bf(v);
        } else {
          float g = 0.5f * v * (1.0f + erff(v * 0.70710678118f));
          ((unsigned short*)Cout)[(long)(row + e) * N + col] = f2bf(g);
        }
      }
    }
  }
}

// ---------------- qkv post: split + add biases (bf16 in, bf16 out) ----------------
__global__ __launch_bounds__(256) void qkv_prep(const unsigned short* __restrict__ q3,
                                                const float* __restrict__ rwb,
                                                const float* __restrict__ rrb,
                                                unsigned short* __restrict__ qw,
                                                unsigned short* __restrict__ qr,
                                                unsigned short* __restrict__ kb) {
  int idx = blockIdx.x * 256 + threadIdx.x;
  int c8 = (idx & 127) * 8;
  int row = idx >> 7;
  int s = row >> 2, b = row & 3;
  int n = c8 >> 6, d = c8 & 63;
  u16x8 qv = *(const u16x8*)&q3[(long)row * 3072 + c8];
  u16x8 kv = *(const u16x8*)&q3[(long)row * 3072 + 1024 + c8];
  long o = ((long)(b * Hh + n) * S + s) * 64 + d;
  u16x8 ow, orr;
#pragma unroll
  for (int e = 0; e < 8; ++e) {
    float q = bf2f(qv[e]);
    ow[e] = f2bf(q + rwb[c8 + e]);
    orr[e] = f2bf(q + rrb[c8 + e]);
  }
  *(u16x8*)&qw[o] = ow;
  *(u16x8*)&qr[o] = orr;
  *(u16x8*)&kb[o] = kv;
}

// ---------------- v transpose: q3 bf16 [S*B,3072] col 2048+ -> vT[B*H, DH, S] ----------------
__global__ __launch_bounds__(256) void vt_prep(const unsigned short* __restrict__ q3,
                                               unsigned short* __restrict__ vT) {
  __shared__ unsigned short tile[64][72];
  const int it = blockIdx.x, bn = blockIdx.y;
  const int nh = bn & 15, bbv = bn >> 4;
  const int t = threadIdx.x;
  const int i0 = t >> 3, c8 = (t & 7) * 8;
#pragma unroll
  for (int c = 0; c < 2; ++c) {
    int i = i0 + c * 32;
    u16x8 v = *(const u16x8*)&q3[((long)(it * 64 + i) * Bb + bbv) * 3072 + 2048 + nh * 64 + c8];
    *(u16x8*)&tile[i][c8] = v;
  }
  __syncthreads();
  for (int cc = t; cc < 512; cc += 256) {
    int d = cc >> 3, i8 = (cc & 7) * 8;
    u16x8 pk;
#pragma unroll
    for (int e = 0; e < 8; ++e) pk[e] = tile[i8 + e][d];
    *(u16x8*)&vT[((long)bn * 64 + d) * S + it * 64 + i8] = pk;
  }
}

// ---------------- rk reorder ----------------
__global__ __launch_bounds__(256) void rkb_prep(const unsigned short* __restrict__ rkall,
                                                unsigned short* __restrict__ rkb) {
  int idx = blockIdx.x * 256 + threadIdx.x;
  int d8 = (idx & 7) * 8;
  int u = (idx >> 3) & 1023;
  int nl = idx >> 13;
  int l = nl >> 4, n = nl & 15;
  u16x8 v = *(const u16x8*)&rkall[(long)u * 4096 + l * 1024 + n * 64 + d8];
  *(u16x8*)&rkb[(long)idx * 8] = v;
}

// ---------------- fused rel-attention (flash), longest-first 1024-grid ----------------
// block = (head bn, q-tile it = 15 - blk/64); heavy tiles dispatch first.
// 41KB LDS -> 3 blocks/CU resident; dynamic refill balances.
__global__ __launch_bounds__(256) void attn_k(const unsigned short* __restrict__ qw,
                                              const unsigned short* __restrict__ qr,
                                              const unsigned short* __restrict__ kbuf,
                                              const unsigned short* __restrict__ vT,
                                              const unsigned short* __restrict__ rk,
                                              unsigned short* __restrict__ vec) {
  __shared__ unsigned short Ks[2][64 * 64];
  __shared__ unsigned short Vs[2][64 * 64];
  __shared__ unsigned short plds[4][16][72];
  const int tid = threadIdx.x, lane = tid & 63, w = tid >> 6;
  const int bn = blockIdx.x & 63;
  const int it = 15 - (blockIdx.x >> 6);
  const int nh = bn & 15, bbv = bn >> 4;
  const int la = lane & 15, hi = lane >> 4, lk = hi * 8;
  const int hi4 = hi * 4;
  const unsigned short* kbase = kbuf + (long)bn * S * 64;
  const unsigned short* vbase = vT + (long)bn * 64 * S;
  const unsigned short* rbase = rk + (long)nh * S * 64;

  const int q0 = w * 128 + lane;
  const int r0 = q0 >> 3, c0s = (q0 & 7) ^ (r0 & 7);
  const int q1 = q0 + 64;
  const int r1 = q1 >> 3, c1s = (q1 & 7) ^ (r1 & 7);

  const int iw = it * 64 + w * 16;
  bf16x8 qwf[2], qrf[2];
  {
    const unsigned short* qp = qw + ((long)bn * S + iw + la) * 64 + lk;
    qwf[0] = *(const bf16x8*)qp;
    qwf[1] = *(const bf16x8*)(qp + 32);
    const unsigned short* qp2 = qr + ((long)bn * S + iw + la) * 64 + lk;
    qrf[0] = *(const bf16x8*)qp2;
    qrf[1] = *(const bf16x8*)(qp2 + 32);
  }
  f32x4 opv[4] = {};
  float m_ = -3e38f;
  float l_[4] = {0.f, 0.f, 0.f, 0.f};
  int cur = 0;

  gload_lds16(kbase + (long)r0 * 64 + c0s * 8, &Ks[cur][w * 1024]);
  gload_lds16(kbase + (long)r1 * 64 + c1s * 8, &Ks[cur][w * 1024 + 512]);
  gload_lds16(vbase + (long)r0 * S + c0s * 8, &Vs[cur][w * 1024]);
  gload_lds16(vbase + (long)r1 * S + c1s * 8, &Vs[cur][w * 1024 + 512]);
  __syncthreads();

  for (int jt = 0; jt <= it; ++jt) {
    const int j0 = jt * 64;
    const bool edge = (jt == it);
    if (jt < it) {
      const int jn = j0 + 64;
      gload_lds16(kbase + (long)(jn + r0) * 64 + c0s * 8, &Ks[cur ^ 1][w * 1024]);
      gload_lds16(kbase + (long)(jn + r1) * 64 + c1s * 8, &Ks[cur ^ 1][w * 1024 + 512]);
      gload_lds16(vbase + (long)r0 * S + jn + c0s * 8, &Vs[cur ^ 1][w * 1024]);
      gload_lds16(vbase + (long)r1 * S + jn + c1s * 8, &Vs[cur ^ 1][w * 1024 + 512]);
    }
    const int u0 = S - 16 - iw + j0;
    bf16x8 rf[10];
#pragma unroll
    for (int g = 0; g < 5; ++g) {
      int u = u0 + g * 16 + la;
      if (edge) u = (u > S - 1) ? (S - 1) : u;
      const unsigned short* rp = rbase + (long)u * 64 + lk;
      rf[2 * g] = *(const bf16x8*)rp;
      rf[2 * g + 1] = *(const bf16x8*)(rp + 32);
    }
    f32x4 ac[4] = {};
#pragma unroll
    for (int f = 0; f < 4; ++f) {
      int row = f * 16 + la;
      const unsigned short* kl = &Ks[cur][row * 64];
      bf16x8 k0 = *(const bf16x8*)(kl + (((hi) ^ (row & 7)) << 3));
      bf16x8 k1 = *(const bf16x8*)(kl + (((hi + 4) ^ (row & 7)) << 3));
      ac[f] = mfma_bf16(qwf[0], k0, ac[f]);
      ac[f] = mfma_bf16(qwf[1], k1, ac[f]);
    }
    f32x4 gg[5] = {};
#pragma unroll
    for (int g = 0; g < 5; ++g) {
      gg[g] = mfma_bf16(qrf[0], rf[2 * g], gg[g]);
      gg[g] = mfma_bf16(qrf[1], rf[2 * g + 1], gg[g]);
    }
    float p[4][4];
#pragma unroll
    for (int f = 0; f < 4; ++f) {
#pragma unroll
      for (int e = 0; e < 4; ++e) {
        int r = hi4 + e;
        float x = (la >= 15 - r) ? gg[f][e] : gg[f + 1][e];
        int src = (lane & 48) | ((la + 15 - r) & 15);
        float bd = __shfl(x, src, 64);
        float sc = (ac[f][e] + bd) * 0.125f;
        if (edge) {
          int i_ = iw + r, j_ = j0 + f * 16 + la;
          sc = (j_ > i_) ? -1e30f : sc;
        }
        p[f][e] = sc;
      }
    }
    float mx = p[0][0];
#pragma unroll
    for (int f = 0; f < 4; ++f)
#pragma unroll
      for (int e = 0; e < 4; ++e) mx = fmaxf(mx, p[f][e]);
#pragma unroll
    for (int o = 1; o < 16; o <<= 1) mx = fmaxf(mx, __shfl_xor(mx, o, 64));
    if (!__all(mx <= m_ + 8.0f)) {
      float mnew = fmaxf(m_, mx);
      float alpha = __expf(m_ - mnew);
      m_ = mnew;
#pragma unroll
      for (int e = 0; e < 4; ++e) l_[e] *= alpha;
#pragma unroll
      for (int d = 0; d < 4; ++d)
#pragma unroll
        for (int e = 0; e < 4; ++e) opv[d][e] *= alpha;
    }
#pragma unroll
    for (int e = 0; e < 4; ++e) {
      float rs = 0.f;
#pragma unroll
      for (int f = 0; f < 4; ++f) {
        p[f][e] = __expf(p[f][e] - m_);
        rs += p[f][e];
      }
      l_[e] += rs;
    }
#pragma unroll
    for (int f = 0; f < 4; ++f)
#pragma unroll
      for (int e = 0; e < 4; ++e)
        plds[w][hi4 + e][f * 16 + la] = f2bf(p[f][e]);
    bf16x8 pa0 = *(const bf16x8*)&plds[w][la][lk];
    bf16x8 pa1 = *(const bf16x8*)&plds[w][la][32 + lk];
#pragma unroll
    for (int d = 0; d < 4; ++d) {
      int dd = d * 16 + la;
      const unsigned short* vl = &Vs[cur][dd * 64];
      bf16x8 v0 = *(const bf16x8*)(vl + (((hi) ^ (dd & 7)) << 3));
      bf16x8 v1 = *(const bf16x8*)(vl + (((hi + 4) ^ (dd & 7)) << 3));
      opv[d] = mfma_bf16(pa0, v0, opv[d]);
      opv[d] = mfma_bf16(pa1, v1, opv[d]);
    }
    __syncthreads();
    if (jt < it) cur ^= 1;
  }
#pragma unroll
  for (int e = 0; e < 4; ++e) {
#pragma unroll
    for (int o = 1; o < 16; o <<= 1) l_[e] += __shfl_xor(l_[e], o, 64);
  }
#pragma unroll
  for (int d = 0; d < 4; ++d) {
#pragma unroll
    for (int e = 0; e < 4; ++e) {
      int i_ = iw + hi4 + e;
      int col = nh * 64 + d * 16 + la;
      vec[((long)i_ * Bb + bbv) * 1024 + col] = f2bf(opv[d][e] / l_[e]);
    }
  }
}

// ---------------- residual add + layernorm ----------------
__global__ __launch_bounds__(256) void add_ln(float* __restrict__ h, const float* __restrict__ x,
                                              const float* __restrict__ g, const float* __restrict__ b,
                                              unsigned short* __restrict__ hb) {
  __shared__ float red[8];
  int row = blockIdx.x, t = threadIdx.x;
  long base = (long)row * 1024 + t * 4;
  f32x4 hv = *(const f32x4*)&h[base];
  f32x4 xv = *(const f32x4*)&x[base];
  f32x4 y = hv + xv;
  float s = y[0] + y[1] + y[2] + y[3];
  float q = y[0] * y[0] + y[1] * y[1] + y[2] * y[2] + y[3] * y[3];
#pragma unroll
  for (int o = 1; o < 64; o <<= 1) {
    s += __shfl_xor(s, o, 64);
    q += __shfl_xor(q, o, 64);
  }
  int w = t >> 6, lane = t & 63;
  if (lane == 0) { red[w] = s; red[4 + w] = q; }
  __syncthreads();
  s = red[0] + red[1] + red[2] + red[3];
  q = red[4] + red[5] + red[6] + red[7];
  float mu = s * (1.0f / 1024.0f);
  float var = q * (1.0f / 1024.0f) - mu * mu;
  float rstd = rsqrtf(var + 1e-5f);
  f32x4 gv = *(const f32x4*)&g[t * 4];
  f32x4 bv = *(const f32x4*)&b[t * 4];
  f32x4 o;
  u16x4 ob;
#pragma unroll
  for (int e = 0; e < 4; ++e) {
    o[e] = (y[e] - mu) * rstd * gv[e] + bv[e];
    ob[e] = f2bf(o[e]);
  }
  *(f32x4*)&h[base] = o;
  *(u16x4*)&hb[base] = ob;
}

extern "C" void kernel_launch(void* const* d_in, const int* in_sizes, int n_in,
                              void* d_out, int out_size, void* d_ws, size_t ws_size,
                              hipStream_t stream) {
  const int* tokens = (const int*)d_in[0];
  const float* word_emb = (const float*)d_in[1];
  const float* rwb = (const float*)d_in[2];
  const float* rrb = (const float*)d_in[3];
  const float* qkv_w = (const float*)d_in[4];
  const float* qkv_b = (const float*)d_in[5];
  const float* r_kw = (const float*)d_in[6];
  const float* r_kb = (const float*)d_in[7];
  const float* o_w = (const float*)d_in[8];
  const float* o_b = (const float*)d_in[9];
  const float* ln1g = (const float*)d_in[10];
  const float* ln1b = (const float*)d_in[11];
  const float* ff1w = (const float*)d_in[12];
  const float* ff1b = (const float*)d_in[13];
  const float* ff2w = (const float*)d_in[14];
  const float* ff2b = (const float*)d_in[15];
  const float* ln2g = (const float*)d_in[16];
  const float* ln2b = (const float*)d_in[17];
  const float* fw = (const float*)d_in[18];
  const float* fb = (const float*)d_in[19];

  char* ws = (char*)d_ws;
  unsigned short* WBF = (unsigned short*)(ws);               // converted weights [Npad,K]
  float* H = (float*)(ws + 33554432);                        // residual f32
  unsigned short* HB = (unsigned short*)(ws + 50331648);     // activations bf16
  unsigned short* GB = (unsigned short*)(ws + 58720256);     // gelu out bf16
  unsigned short* RBF = (unsigned short*)(ws + 92274688);    // pos-emb bf16

  char* ob = (char*)d_out;
  float* OUTF = (float*)ob;
  unsigned short* OUTH = (unsigned short*)ob;
  unsigned short* QW = (unsigned short*)(ob + 67108864);
  unsigned short* QR = (unsigned short*)(ob + 75497472);
  unsigned short* KB = (unsigned short*)(ob + 83886080);
  unsigned short* VT = (unsigned short*)(ob + 92274688);
  unsigned short* RKB = (unsigned short*)(ob + 100663296);
  float* OUT = (float*)d_out;

  embed_k<<<4096, 256, 0, stream>>>(tokens, word_emb, H, HB);
  posr_k<<<4096, 256, 0, stream>>>(RBF);
  wcvt_t<<<dim3(32, 32, 4), 256, 0, stream>>>(r_kw, WBF, 1024, 1024);
  gemm_bt<1><<<256, 256, 0, stream>>>(RBF, WBF, r_kb, OUTH, 1024, 4096, 1024, 32);
  rkb_prep<<<2048, 256, 0, stream>>>(OUTH, RKB);

  for (int l = 0; l < Lll; ++l) {
    wcvt_t<<<dim3(96, 32, 1), 256, 0, stream>>>(qkv_w + (long)l * 1024 * 3072, WBF, 1024, 3072);
    gemm_bt<1><<<768, 256, 0, stream>>>(HB, WBF, qkv_b + l * 3072, OUTH, 4096, 3072, 1024, 24);
    qkv_prep<<<2048, 256, 0, stream>>>(OUTH, rwb, rrb, QW, QR, KB);
    vt_prep<<<dim3(16, 64), 256, 0, stream>>>(OUTH, VT);
    attn_k<<<1024, 256, 0, stream>>>(QW, QR, KB, VT, RKB + (long)l * Hh * S * 64, HB);
    wcvt_t<<<dim3(32, 32, 1), 256, 0, stream>>>(o_w + (long)l * 1024 * 1024, WBF, 1024, 1024);
    gemm_bt64<0><<<512, 256, 0, stream>>>(HB, WBF, o_b + l * 1024, OUTF, 4096, 1024, 1024, 8);
    add_ln<<<4096, 256, 0, stream>>>(H, OUTF, ln1g + l * 1024, ln1b + l * 1024, HB);

    wcvt_t<<<dim3(128, 32, 1), 256, 0, stream>>>(ff1w + (long)l * 1024 * 4096, WBF, 1024, 4096);
    gemm_bt<2><<<1024, 256, 0, stream>>>(HB, WBF, ff1b + l * 4096, GB, 4096, 4096, 1024, 32);
    wcvt_t<<<dim3(32, 128, 1), 256, 0, stream>>>(ff2w + (long)l * 4096 * 1024, WBF, 4096, 1024);
    gemm_bt64<0><<<512, 256, 0, stream>>>(GB, WBF, ff2b + l * 1024, OUTF, 4096, 1024, 4096, 8);
    add_ln<<<4096, 256, 0, stream>>>(H, OUTF, ln2g + l * 1024, ln2b + l * 1024, HB);
  }

  // final: pad N to 16128 (63*256); bm-major for B-panel L2 reuse
  wcvt_t<<<dim3(504, 32, 1), 256, 0, stream>>>(fw, WBF, 1024, 16000);
  gemm256<0><<<1008, 512, 0, stream>>>(HB, WBF, fb, OUT, 4096, 16000, 1024, 16, 63, 1);
}